// Round 11
// baseline (354.663 us; speedup 1.0000x reference)
//
#include <hip/hip_runtime.h>

// MQA: B=2, S=2048, HID=2048, NH=16, HD=128
#define B_   2
#define S_   2048
#define HID_ 2048
#define NH_  16
#define HD_  128
#define M_   (B_ * S_)   // 4096 total rows

using half4    = __attribute__((ext_vector_type(4))) _Float16;
using half8    = __attribute__((ext_vector_type(8))) _Float16;
using floatx4  = __attribute__((ext_vector_type(4))) float;
using floatx16 = __attribute__((ext_vector_type(16))) float;

// async global->LDS, 16B per lane (LDS dst = wave-uniform base + lane*16)
__device__ __forceinline__ void gl_lds16(const void* g, void* l) {
  __builtin_amdgcn_global_load_lds(
      (const __attribute__((address_space(1))) void*)g,
      (__attribute__((address_space(3))) void*)l, 16, 0, 0);
}

__device__ __forceinline__ void cvt8(const float* s, _Float16* d, int i) {
  const floatx4* sp = (const floatx4*)s;
  floatx4 a = sp[(size_t)i * 2];
  floatx4 b = sp[(size_t)i * 2 + 1];
  half8 h;
  h[0] = (_Float16)a[0]; h[1] = (_Float16)a[1];
  h[2] = (_Float16)a[2]; h[3] = (_Float16)a[3];
  h[4] = (_Float16)b[0]; h[5] = (_Float16)b[1];
  h[6] = (_Float16)b[2]; h[7] = (_Float16)b[3];
  *(half8*)(d + (size_t)i * 8) = h;
}

// ---------------------------------------------------------------------------
// One fused fp32->fp16 cast for hidden + all 4 weights (2048 elems/blk)
// ---------------------------------------------------------------------------
__global__ __launch_bounds__(256) void cvt_all(
    const float* __restrict__ h,  const float* __restrict__ wq,
    const float* __restrict__ wk, const float* __restrict__ wv,
    const float* __restrict__ wo,
    _Float16* __restrict__ dh,  _Float16* __restrict__ dwq,
    _Float16* __restrict__ dwk, _Float16* __restrict__ dwv,
    _Float16* __restrict__ dwo) {
  int bid = blockIdx.x;
  const float* s;
  _Float16* d;
  int off;
  if (bid < 4096)      { s = h;  d = dh;  off = bid; }
  else if (bid < 6144) { s = wq; d = dwq; off = bid - 4096; }
  else if (bid < 6272) { s = wk; d = dwk; off = bid - 6144; }
  else if (bid < 6400) { s = wv; d = dwv; off = bid - 6272; }
  else                 { s = wo; d = dwo; off = bid - 6400; }
  cvt8(s, d, off * 256 + threadIdx.x);
}

// ---------------------------------------------------------------------------
// GEMM body: C[M,N] = A[M,K] @ W[N,K]^T + bias. 128x128 tile, BK=32 (m97
// structure, round-7-measured best), unpadded 32-half LDS rows,
// global_load_lds width=16 staging. MFMA = 32x32x16_f16: 8 ds_read_b128 +
// 8 MFMA per iteration (vs 16 MFMA with 16x16x32).
// A/B frag: idx=lane&31, k=(lane>>5)*8+j. C/D: col=lane&31,
// row=(reg&3)+8*(reg>>2)+4*(lane>>5)  [verified m74/m101].
// TRANS: store transposed as C[b][col][s] (for V^T).
// ---------------------------------------------------------------------------
template <typename OutT, bool TRANS>
__device__ __forceinline__ void gemm128_body(
    const _Float16* __restrict__ A, const _Float16* __restrict__ W,
    const float* __restrict__ bias, OutT* __restrict__ C,
    int Nout, int K, int m0, int n0w, int c0) {
  __shared__ __align__(16) _Float16 As[128][32];  // 8 KB, 64-B rows
  __shared__ __align__(16) _Float16 Ws[128][32];

  const int tid  = threadIdx.x;
  const int lane = tid & 63;
  const int wave = tid >> 6;
  const int wm   = wave >> 1, wn = wave & 1;
  const int l31  = lane & 31, lh = lane >> 5;
  const int srow = wave * 16 + (lane >> 2);
  const int scol = (lane & 3) * 8;

  floatx16 acc[2][2];
#pragma unroll
  for (int i = 0; i < 2; i++)
#pragma unroll
    for (int j = 0; j < 2; j++)
#pragma unroll
      for (int r = 0; r < 16; r++) acc[i][j][r] = 0.f;

  const _Float16* Ag = A + (size_t)(m0 + srow) * K + scol;
  const _Float16* Wg = W + (size_t)(n0w + srow) * K + scol;
  const size_t step64 = (size_t)64 * K;

  for (int kt = 0; kt < K; kt += 32) {
    gl_lds16(Ag + kt,          &As[wave * 16][0]);
    gl_lds16(Ag + step64 + kt, &As[64 + wave * 16][0]);
    gl_lds16(Wg + kt,          &Ws[wave * 16][0]);
    gl_lds16(Wg + step64 + kt, &Ws[64 + wave * 16][0]);
    __syncthreads();

#pragma unroll
    for (int kd = 0; kd < 2; kd++) {
      half8 af[2], bf[2];
#pragma unroll
      for (int i = 0; i < 2; i++)
        af[i] = *(const half8*)&As[wm * 64 + i * 32 + l31][kd * 16 + lh * 8];
#pragma unroll
      for (int j = 0; j < 2; j++)
        bf[j] = *(const half8*)&Ws[wn * 64 + j * 32 + l31][kd * 16 + lh * 8];
#pragma unroll
      for (int i = 0; i < 2; i++)
#pragma unroll
        for (int j = 0; j < 2; j++)
          acc[i][j] = __builtin_amdgcn_mfma_f32_32x32x16_f16(af[i], bf[j], acc[i][j], 0, 0, 0);
    }
    __syncthreads();
  }

  if constexpr (TRANS) {
    // V^T epilogue: C layout [b][d=col][s]; kv rows r+8g+4lh are half4 over r
    const int b  = m0 / S_;
    const int sb = m0 - b * S_ + wm * 64;
#pragma unroll
    for (int j = 0; j < 2; j++) {
      int col  = wn * 64 + j * 32 + l31;
      float bv = bias[n0w + col];
#pragma unroll
      for (int i = 0; i < 2; i++)
#pragma unroll
        for (int g = 0; g < 4; g++) {
          half4 o;
#pragma unroll
          for (int r = 0; r < 4; r++) o[r] = (_Float16)(acc[i][j][g * 4 + r] + bv);
          *(half4*)((_Float16*)C + (size_t)b * HD_ * S_ + (size_t)col * S_
                    + sb + i * 32 + g * 8 + lh * 4) = o;
        }
    }
  } else {
#pragma unroll
    for (int j = 0; j < 2; j++) {
      int col_l = wn * 64 + j * 32 + l31;
      float bv  = bias[n0w + col_l];
#pragma unroll
      for (int i = 0; i < 2; i++)
#pragma unroll
        for (int g = 0; g < 4; g++) {
          int row = m0 + wm * 64 + i * 32 + g * 8 + lh * 4;
#pragma unroll
          for (int r = 0; r < 4; r++)
            C[(size_t)(row + r) * Nout + c0 + col_l] = (OutT)(acc[i][j][g * 4 + r] + bv);
        }
    }
  }
}

// Fused Q/K/V projection: grid.x = 18 column tiles (16 Q + 1 K + 1 V->V^T)
__global__ __launch_bounds__(256) void gemm_qkv(
    const _Float16* __restrict__ A,
    const _Float16* __restrict__ Wq, const float* __restrict__ bq, _Float16* __restrict__ Qh,
    const _Float16* __restrict__ Wk, const float* __restrict__ bk, _Float16* __restrict__ Kh,
    const _Float16* __restrict__ Wv, const float* __restrict__ bv, _Float16* __restrict__ VhT) {
  const int nt = blockIdx.x, m0 = blockIdx.y * 128;
  if (nt < 16)
    gemm128_body<_Float16, false>(A, Wq, bq, Qh, HID_, HID_, m0, nt * 128, nt * 128);
  else if (nt == 16)
    gemm128_body<_Float16, false>(A, Wk, bk, Kh, HD_, HID_, m0, 0, 0);
  else
    gemm128_body<_Float16, true>(A, Wv, bv, VhT, HD_, HID_, m0, 0, 0);
}

__global__ __launch_bounds__(256) void gemm_out(
    const _Float16* __restrict__ A, const _Float16* __restrict__ W,
    const float* __restrict__ bias, float* __restrict__ C) {
  gemm128_body<float, false>(A, W, bias, C, HID_, HID_, blockIdx.y * 128,
                             blockIdx.x * 128, blockIdx.x * 128);
}

// ---------------------------------------------------------------------------
// MFMA flash attention (round-10 version, best measured: S^T formulation,
// double-buffered K/V LDS, register prefetch, one barrier per KV tile,
// deferred l reduction, rescale skip).
// Do NOT tighten __launch_bounds__: body needs ~128 arch VGPRs + 64 acc;
// (256,4) forced 64 VGPRs -> ~2 GB scratch spill (round-8 counters).
// ---------------------------------------------------------------------------
__global__ __launch_bounds__(256, 2) void attn_mfma(
    const _Float16* __restrict__ Q, const _Float16* __restrict__ K,
    const _Float16* __restrict__ VhT, const int* __restrict__ mask,
    _Float16* __restrict__ Obuf) {
  constexpr int BN = 64, KP = 136, VP = 72, NT = S_ / BN;
  __shared__ __align__(16) _Float16 Ks[2][BN][KP];   // 34.8 KB
  __shared__ __align__(16) _Float16 Vt[2][HD_][VP];  // 36.9 KB

  const int tid  = threadIdx.x;
  const int lane = tid & 63, wave = tid >> 6;
  const int l15  = lane & 15, lq = lane >> 4;
  const int q0   = blockIdx.x * 128;
  const int b    = blockIdx.y >> 4, h = blockIdx.y & 15;
  const float sl2e = 0.08838834764831845f * 1.44269504088896341f;  // scale*log2e
  const _Float16* VT = VhT + (size_t)b * HD_ * S_;
  const _Float16* Kb = K + (size_t)b * S_ * HD_;
  const int* mb = mask + b * S_;

  int krow[4], kcol[4], vrow[4], vcol[4];
#pragma unroll
  for (int it = 0; it < 4; it++) {
    int i = it * 256 + tid;
    krow[it] = i >> 4;  kcol[it] = (i & 15) * 8;
    vrow[it] = i >> 3;  vcol[it] = (i & 7) * 8;
  }

  // Q fragments (B-operand of S^T mfma): m=l15, d=lq*8+j
  half8 qf[2][4];
#pragma unroll
  for (int i = 0; i < 2; i++)
#pragma unroll
    for (int kd = 0; kd < 4; kd++)
      qf[i][kd] = *(const half8*)(Q + (size_t)(b * S_ + q0 + wave * 32 + i * 16 + l15) * HID_
                                  + h * HD_ + kd * 32 + lq * 8);

  float m_i[2] = {-3.0e38f, -3.0e38f};
  float l_p[2] = {0.f, 0.f};   // per-lane partial of l
  floatx4 oacc[2][8];
#pragma unroll
  for (int i = 0; i < 2; i++)
#pragma unroll
    for (int jd = 0; jd < 8; jd++) oacc[i][jd] = (floatx4){0.f, 0.f, 0.f, 0.f};

  half8 kreg[4], vreg[4];
  // prologue: tile 0 -> regs -> buf 0
#pragma unroll
  for (int it = 0; it < 4; it++) {
    kreg[it] = *(const half8*)(Kb + (size_t)krow[it] * HD_ + kcol[it]);
    vreg[it] = *(const half8*)(VT + (size_t)vrow[it] * S_ + vcol[it]);
  }
#pragma unroll
  for (int it = 0; it < 4; it++) {
    *(half8*)&Ks[0][krow[it]][kcol[it]] = kreg[it];
    *(half8*)&Vt[0][vrow[it]][vcol[it]] = vreg[it];
  }
  __syncthreads();

  for (int t = 0; t < NT; t++) {
    const int cur = t & 1;
    const int n0  = t * BN;
    const bool has_next = (t + 1) < NT;

    if (has_next) {
      const int nn = n0 + BN;
#pragma unroll
      for (int it = 0; it < 4; it++) {
        kreg[it] = *(const half8*)(Kb + (size_t)(nn + krow[it]) * HD_ + kcol[it]);
        vreg[it] = *(const half8*)(VT + (size_t)vrow[it] * S_ + nn + vcol[it]);
      }
    }

    int4 mk4[4];
#pragma unroll
    for (int j = 0; j < 4; j++)
      mk4[j] = *(const int4*)(mb + n0 + j * 16 + lq * 4);

    // ---- S^T = K Q^T : st[j][i], n = j*16+lq*4+r, m = i*16+l15 (+wave*32)
    floatx4 st[4][2];
#pragma unroll
    for (int j = 0; j < 4; j++)
#pragma unroll
      for (int i = 0; i < 2; i++) st[j][i] = (floatx4){0.f, 0.f, 0.f, 0.f};
#pragma unroll
    for (int kd = 0; kd < 4; kd++) {
      half8 kb[4];
#pragma unroll
      for (int j = 0; j < 4; j++)
        kb[j] = *(const half8*)&Ks[cur][j * 16 + l15][kd * 32 + lq * 8];
#pragma unroll
      for (int j = 0; j < 4; j++)
#pragma unroll
        for (int i = 0; i < 2; i++)
          st[j][i] = __builtin_amdgcn_mfma_f32_16x16x32_f16(kb[j], qf[i][kd], st[j][i], 0, 0, 0);
    }

    floatx4 amf[4];
#pragma unroll
    for (int j = 0; j < 4; j++) {
      amf[j][0] = mk4[j].x ? 0.f : -3.0e38f;
      amf[j][1] = mk4[j].y ? 0.f : -3.0e38f;
      amf[j][2] = mk4[j].z ? 0.f : -3.0e38f;
      amf[j][3] = mk4[j].w ? 0.f : -3.0e38f;
    }

    // ---- online softmax (2 shfls for max; l as lane partial)
    half4 ph[2][4];
#pragma unroll
    for (int i = 0; i < 2; i++) {
      float mx = -3.0e38f;
#pragma unroll
      for (int j = 0; j < 4; j++)
#pragma unroll
        for (int r = 0; r < 4; r++) {
          float v = st[j][i][r] * sl2e + amf[j][r];
          st[j][i][r] = v;
          mx = fmaxf(mx, v);
        }
      mx = fmaxf(mx, __shfl_xor(mx, 16));
      mx = fmaxf(mx, __shfl_xor(mx, 32));
      float mnew  = fmaxf(m_i[i], mx);
      float alpha = __builtin_amdgcn_exp2f(m_i[i] - mnew);
      m_i[i] = mnew;
      float rs = 0.f;
#pragma unroll
      for (int j = 0; j < 4; j++)
#pragma unroll
        for (int r = 0; r < 4; r++) {
          float pv = __builtin_amdgcn_exp2f(st[j][i][r] - mnew);
          ph[i][j][r] = (_Float16)pv;
          rs += pv;
        }
      l_p[i] = l_p[i] * alpha + rs;
      if (__any(alpha < 1.0f)) {
#pragma unroll
        for (int r = 0; r < 4; r++) {
          float a_r = __shfl(alpha, lq * 4 + r);
#pragma unroll
          for (int jd = 0; jd < 8; jd++) oacc[i][jd][r] *= a_r;
        }
      }
    }

    // ---- O += P V via 16x16x16 (A = ph in-register, B = Vt half4)
#pragma unroll
    for (int j = 0; j < 4; j++) {
#pragma unroll
      for (int jd = 0; jd < 8; jd++) {
        half4 vb = *(const half4*)&Vt[cur][jd * 16 + l15][j * 16 + lq * 4];
#pragma unroll
        for (int i = 0; i < 2; i++)
          oacc[i][jd] = __builtin_amdgcn_mfma_f32_16x16x16f16(ph[i][j], vb, oacc[i][jd], 0, 0, 0);
      }
    }

    if (has_next) {
      const int nxt = 1 - cur;
#pragma unroll
      for (int it = 0; it < 4; it++) {
        *(half8*)&Ks[nxt][krow[it]][kcol[it]] = kreg[it];
        *(half8*)&Vt[nxt][vrow[it]][vcol[it]] = vreg[it];
      }
    }
    __syncthreads();
  }

  // ---- final l reduction + epilogue
#pragma unroll
  for (int i = 0; i < 2; i++) {
    float l = l_p[i];
    l += __shfl_xor(l, 16);
    l += __shfl_xor(l, 32);
    float linv = 1.0f / l;
#pragma unroll
    for (int r = 0; r < 4; r++) {
      float lr = __shfl(linv, lq * 4 + r);
      size_t row = (size_t)(b * S_ + q0 + wave * 32 + i * 16 + lq * 4 + r);
#pragma unroll
      for (int jd = 0; jd < 8; jd++)
        Obuf[row * HID_ + h * HD_ + jd * 16 + l15] = (_Float16)(oacc[i][jd][r] * lr);
    }
  }
}

// ---------------------------------------------------------------------------
extern "C" void kernel_launch(void* const* d_in, const int* in_sizes, int n_in,
                              void* d_out, int out_size, void* d_ws, size_t ws_size,
                              hipStream_t stream) {
  const float* hidden = (const float*)d_in[0];
  const int*   mask   = (const int*)d_in[1];
  const float* Wq = (const float*)d_in[2];
  const float* bq = (const float*)d_in[3];
  const float* Wk = (const float*)d_in[4];
  const float* bk = (const float*)d_in[5];
  const float* Wv = (const float*)d_in[6];
  const float* bv = (const float*)d_in[7];
  const float* Wo = (const float*)d_in[8];
  const float* bo = (const float*)d_in[9];
  float* out = (float*)d_out;

  char* p = (char*)d_ws;
  auto alloc = [&](size_t bytes) {
    char* r = p;
    p += (bytes + 255) & ~(size_t)255;
    return r;
  };
  _Float16* hidh  = (_Float16*)alloc((size_t)M_ * HID_ * 2);
  _Float16* Wqh   = (_Float16*)alloc((size_t)HID_ * HID_ * 2);
  _Float16* Wkh   = (_Float16*)alloc((size_t)HD_ * HID_ * 2);
  _Float16* Wvh   = (_Float16*)alloc((size_t)HD_ * HID_ * 2);
  _Float16* Woh   = (_Float16*)alloc((size_t)HID_ * HID_ * 2);
  _Float16* Qh    = (_Float16*)alloc((size_t)M_ * HID_ * 2);
  _Float16* Kh    = (_Float16*)alloc((size_t)M_ * HD_ * 2);
  _Float16* VhT   = (_Float16*)alloc((size_t)M_ * HD_ * 2);
  _Float16* attnh = (_Float16*)alloc((size_t)M_ * HID_ * 2);

  // one fused fp32 -> fp16 cast (8448 blocks)
  cvt_all<<<8448, 256, 0, stream>>>(hidden, Wq, Wk, Wv, Wo,
                                    hidh, Wqh, Wkh, Wvh, Woh);

  // fused Q/K/V projection (V written transposed): 18 x 32 tiles
  dim3 gqkv(18, M_ / 128);
  gemm_qkv<<<gqkv, 256, 0, stream>>>(hidh, Wqh, bq, Qh, Wkh, bk, Kh, Wvh, bv, VhT);

  // attention (S^T flash, dbuf K/V, round-10 structure)
  dim3 ga(S_ / 128, B_ * NH_);  // (16, 32)
  attn_mfma<<<ga, 256, 0, stream>>>(Qh, Kh, VhT, mask, attnh);

  // output projection -> d_out (fp32)
  dim3 go(HID_ / 128, M_ / 128);
  gemm_out<<<go, 256, 0, stream>>>(attnh, Woh, bo, out);
}

// Round 12
// 317.536 us; speedup vs baseline: 1.1169x; 1.1169x over previous
//
#include <hip/hip_runtime.h>

// MQA: B=2, S=2048, HID=2048, NH=16, HD=128
#define B_   2
#define S_   2048
#define HID_ 2048
#define NH_  16
#define HD_  128
#define M_   (B_ * S_)   // 4096 total rows

using half4   = __attribute__((ext_vector_type(4))) _Float16;
using half8   = __attribute__((ext_vector_type(8))) _Float16;
using floatx4 = __attribute__((ext_vector_type(4))) float;

// async global->LDS, 16B per lane (LDS dst = wave-uniform base + lane*16)
__device__ __forceinline__ void gl_lds16(const void* g, void* l) {
  __builtin_amdgcn_global_load_lds(
      (const __attribute__((address_space(1))) void*)g,
      (__attribute__((address_space(3))) void*)l, 16, 0, 0);
}

__device__ __forceinline__ void cvt8(const float* s, _Float16* d, int i) {
  const floatx4* sp = (const floatx4*)s;
  floatx4 a = sp[(size_t)i * 2];
  floatx4 b = sp[(size_t)i * 2 + 1];
  half8 h;
  h[0] = (_Float16)a[0]; h[1] = (_Float16)a[1];
  h[2] = (_Float16)a[2]; h[3] = (_Float16)a[3];
  h[4] = (_Float16)b[0]; h[5] = (_Float16)b[1];
  h[6] = (_Float16)b[2]; h[7] = (_Float16)b[3];
  *(half8*)(d + (size_t)i * 8) = h;
}

// ---------------------------------------------------------------------------
// One fused fp32->fp16 cast for hidden + all 4 weights (2048 elems/blk)
// ---------------------------------------------------------------------------
__global__ __launch_bounds__(256) void cvt_all(
    const float* __restrict__ h,  const float* __restrict__ wq,
    const float* __restrict__ wk, const float* __restrict__ wv,
    const float* __restrict__ wo,
    _Float16* __restrict__ dh,  _Float16* __restrict__ dwq,
    _Float16* __restrict__ dwk, _Float16* __restrict__ dwv,
    _Float16* __restrict__ dwo) {
  int bid = blockIdx.x;
  const float* s;
  _Float16* d;
  int off;
  if (bid < 4096)      { s = h;  d = dh;  off = bid; }
  else if (bid < 6144) { s = wq; d = dwq; off = bid - 4096; }
  else if (bid < 6272) { s = wk; d = dwk; off = bid - 6144; }
  else if (bid < 6400) { s = wv; d = dwv; off = bid - 6272; }
  else                 { s = wo; d = dwo; off = bid - 6400; }
  cvt8(s, d, off * 256 + threadIdx.x);
}

// ---------------------------------------------------------------------------
// m97-style GEMM body (round-7 version — measured local optimum):
// C[M,N] = A[M,K] @ W[N,K]^T + bias. 128x128 tile, BK=32, unpadded 32-half
// LDS rows, global_load_lds width=16 staging, 16x16x32 MFMA.
// Measured regressions, do NOT redo: BK=64 (+7 us, m132-style occupancy
// loss), 32x32x16 MFMA (+27 us: only 2 distinct row start-banks at 64-B
// rows + 2 column windows -> ds_read_b128 conflicts).
// TRANS: store transposed as C[b][col][s] (for V^T).
// ---------------------------------------------------------------------------
template <typename OutT, bool TRANS>
__device__ __forceinline__ void gemm128_body(
    const _Float16* __restrict__ A, const _Float16* __restrict__ W,
    const float* __restrict__ bias, OutT* __restrict__ C,
    int Nout, int K, int m0, int n0w, int c0) {
  __shared__ __align__(16) _Float16 As[128][32];  // 8 KB
  __shared__ __align__(16) _Float16 Ws[128][32];

  const int tid  = threadIdx.x;
  const int lane = tid & 63;
  const int wave = tid >> 6;
  const int wm   = wave >> 1, wn = wave & 1;
  const int l15  = lane & 15, lq = lane >> 4;
  const int srow = wave * 16 + (lane >> 2);
  const int scol = (lane & 3) * 8;

  floatx4 acc[4][4];
#pragma unroll
  for (int i = 0; i < 4; i++)
#pragma unroll
    for (int j = 0; j < 4; j++) acc[i][j] = (floatx4){0.f, 0.f, 0.f, 0.f};

  const _Float16* Ag = A + (size_t)(m0 + srow) * K + scol;
  const _Float16* Wg = W + (size_t)(n0w + srow) * K + scol;
  const size_t step64 = (size_t)64 * K;

  for (int kt = 0; kt < K; kt += 32) {
    gl_lds16(Ag + kt,          &As[wave * 16][0]);
    gl_lds16(Ag + step64 + kt, &As[64 + wave * 16][0]);
    gl_lds16(Wg + kt,          &Ws[wave * 16][0]);
    gl_lds16(Wg + step64 + kt, &Ws[64 + wave * 16][0]);
    __syncthreads();

    half8 af[4], bf[4];
#pragma unroll
    for (int i = 0; i < 4; i++)
      af[i] = *(const half8*)&As[wm * 64 + i * 16 + l15][lq * 8];
#pragma unroll
    for (int j = 0; j < 4; j++)
      bf[j] = *(const half8*)&Ws[wn * 64 + j * 16 + l15][lq * 8];
#pragma unroll
    for (int i = 0; i < 4; i++)
#pragma unroll
      for (int j = 0; j < 4; j++)
        acc[i][j] = __builtin_amdgcn_mfma_f32_16x16x32_f16(af[i], bf[j], acc[i][j], 0, 0, 0);
    __syncthreads();
  }

  const int rq = lq * 4;
  if constexpr (TRANS) {
    const int b  = m0 / S_;
    const int sb = m0 - b * S_ + wm * 64;
#pragma unroll
    for (int j = 0; j < 4; j++) {
      int col  = wn * 64 + j * 16 + l15;
      float bv = bias[n0w + col];
#pragma unroll
      for (int i = 0; i < 4; i++) {
        half4 o;
#pragma unroll
        for (int r = 0; r < 4; r++) o[r] = (_Float16)(acc[i][j][r] + bv);
        *(half4*)((_Float16*)C + (size_t)b * HD_ * S_ + (size_t)col * S_
                  + sb + i * 16 + rq) = o;
      }
    }
  } else {
#pragma unroll
    for (int j = 0; j < 4; j++) {
      int col_l = wn * 64 + j * 16 + l15;
      float bv  = bias[n0w + col_l];
#pragma unroll
      for (int i = 0; i < 4; i++) {
        int row = m0 + wm * 64 + i * 16 + rq;
#pragma unroll
        for (int r = 0; r < 4; r++)
          C[(size_t)(row + r) * Nout + c0 + col_l] = (OutT)(acc[i][j][r] + bv);
      }
    }
  }
}

// Fused Q/K/V projection: grid.x = 18 column tiles (16 Q + 1 K + 1 V->V^T)
__global__ __launch_bounds__(256) void gemm_qkv(
    const _Float16* __restrict__ A,
    const _Float16* __restrict__ Wq, const float* __restrict__ bq, _Float16* __restrict__ Qh,
    const _Float16* __restrict__ Wk, const float* __restrict__ bk, _Float16* __restrict__ Kh,
    const _Float16* __restrict__ Wv, const float* __restrict__ bv, _Float16* __restrict__ VhT) {
  const int nt = blockIdx.x, m0 = blockIdx.y * 128;
  if (nt < 16)
    gemm128_body<_Float16, false>(A, Wq, bq, Qh, HID_, HID_, m0, nt * 128, nt * 128);
  else if (nt == 16)
    gemm128_body<_Float16, false>(A, Wk, bk, Kh, HD_, HID_, m0, 0, 0);
  else
    gemm128_body<_Float16, true>(A, Wv, bv, VhT, HD_, HID_, m0, 0, 0);
}

__global__ __launch_bounds__(256) void gemm_out(
    const _Float16* __restrict__ A, const _Float16* __restrict__ W,
    const float* __restrict__ bias, float* __restrict__ C) {
  gemm128_body<float, false>(A, W, bias, C, HID_, HID_, blockIdx.y * 128,
                             blockIdx.x * 128, blockIdx.x * 128);
}

// ---------------------------------------------------------------------------
// MFMA flash attention (round-10/11 version, best measured: S^T formulation,
// double-buffered K/V LDS, register prefetch, one barrier per KV tile,
// deferred l reduction, rescale skip).
// Do NOT tighten __launch_bounds__: body needs ~128 arch VGPRs + 64 acc;
// (256,4) forced 64 VGPRs -> ~2 GB scratch spill (round-8 counters).
// ---------------------------------------------------------------------------
__global__ __launch_bounds__(256, 2) void attn_mfma(
    const _Float16* __restrict__ Q, const _Float16* __restrict__ K,
    const _Float16* __restrict__ VhT, const int* __restrict__ mask,
    _Float16* __restrict__ Obuf) {
  constexpr int BN = 64, KP = 136, VP = 72, NT = S_ / BN;
  __shared__ __align__(16) _Float16 Ks[2][BN][KP];   // 34.8 KB
  __shared__ __align__(16) _Float16 Vt[2][HD_][VP];  // 36.9 KB

  const int tid  = threadIdx.x;
  const int lane = tid & 63, wave = tid >> 6;
  const int l15  = lane & 15, lq = lane >> 4;
  const int q0   = blockIdx.x * 128;
  const int b    = blockIdx.y >> 4, h = blockIdx.y & 15;
  const float sl2e = 0.08838834764831845f * 1.44269504088896341f;  // scale*log2e
  const _Float16* VT = VhT + (size_t)b * HD_ * S_;
  const _Float16* Kb = K + (size_t)b * S_ * HD_;
  const int* mb = mask + b * S_;

  int krow[4], kcol[4], vrow[4], vcol[4];
#pragma unroll
  for (int it = 0; it < 4; it++) {
    int i = it * 256 + tid;
    krow[it] = i >> 4;  kcol[it] = (i & 15) * 8;
    vrow[it] = i >> 3;  vcol[it] = (i & 7) * 8;
  }

  // Q fragments (B-operand of S^T mfma): m=l15, d=lq*8+j
  half8 qf[2][4];
#pragma unroll
  for (int i = 0; i < 2; i++)
#pragma unroll
    for (int kd = 0; kd < 4; kd++)
      qf[i][kd] = *(const half8*)(Q + (size_t)(b * S_ + q0 + wave * 32 + i * 16 + l15) * HID_
                                  + h * HD_ + kd * 32 + lq * 8);

  float m_i[2] = {-3.0e38f, -3.0e38f};
  float l_p[2] = {0.f, 0.f};   // per-lane partial of l
  floatx4 oacc[2][8];
#pragma unroll
  for (int i = 0; i < 2; i++)
#pragma unroll
    for (int jd = 0; jd < 8; jd++) oacc[i][jd] = (floatx4){0.f, 0.f, 0.f, 0.f};

  half8 kreg[4], vreg[4];
  // prologue: tile 0 -> regs -> buf 0
#pragma unroll
  for (int it = 0; it < 4; it++) {
    kreg[it] = *(const half8*)(Kb + (size_t)krow[it] * HD_ + kcol[it]);
    vreg[it] = *(const half8*)(VT + (size_t)vrow[it] * S_ + vcol[it]);
  }
#pragma unroll
  for (int it = 0; it < 4; it++) {
    *(half8*)&Ks[0][krow[it]][kcol[it]] = kreg[it];
    *(half8*)&Vt[0][vrow[it]][vcol[it]] = vreg[it];
  }
  __syncthreads();

  for (int t = 0; t < NT; t++) {
    const int cur = t & 1;
    const int n0  = t * BN;
    const bool has_next = (t + 1) < NT;

    if (has_next) {
      const int nn = n0 + BN;
#pragma unroll
      for (int it = 0; it < 4; it++) {
        kreg[it] = *(const half8*)(Kb + (size_t)(nn + krow[it]) * HD_ + kcol[it]);
        vreg[it] = *(const half8*)(VT + (size_t)vrow[it] * S_ + nn + vcol[it]);
      }
    }

    int4 mk4[4];
#pragma unroll
    for (int j = 0; j < 4; j++)
      mk4[j] = *(const int4*)(mb + n0 + j * 16 + lq * 4);

    // ---- S^T = K Q^T : st[j][i], n = j*16+lq*4+r, m = i*16+l15 (+wave*32)
    floatx4 st[4][2];
#pragma unroll
    for (int j = 0; j < 4; j++)
#pragma unroll
      for (int i = 0; i < 2; i++) st[j][i] = (floatx4){0.f, 0.f, 0.f, 0.f};
#pragma unroll
    for (int kd = 0; kd < 4; kd++) {
      half8 kb[4];
#pragma unroll
      for (int j = 0; j < 4; j++)
        kb[j] = *(const half8*)&Ks[cur][j * 16 + l15][kd * 32 + lq * 8];
#pragma unroll
      for (int j = 0; j < 4; j++)
#pragma unroll
        for (int i = 0; i < 2; i++)
          st[j][i] = __builtin_amdgcn_mfma_f32_16x16x32_f16(kb[j], qf[i][kd], st[j][i], 0, 0, 0);
    }

    floatx4 amf[4];
#pragma unroll
    for (int j = 0; j < 4; j++) {
      amf[j][0] = mk4[j].x ? 0.f : -3.0e38f;
      amf[j][1] = mk4[j].y ? 0.f : -3.0e38f;
      amf[j][2] = mk4[j].z ? 0.f : -3.0e38f;
      amf[j][3] = mk4[j].w ? 0.f : -3.0e38f;
    }

    // ---- online softmax (2 shfls for max; l as lane partial)
    half4 ph[2][4];
#pragma unroll
    for (int i = 0; i < 2; i++) {
      float mx = -3.0e38f;
#pragma unroll
      for (int j = 0; j < 4; j++)
#pragma unroll
        for (int r = 0; r < 4; r++) {
          float v = st[j][i][r] * sl2e + amf[j][r];
          st[j][i][r] = v;
          mx = fmaxf(mx, v);
        }
      mx = fmaxf(mx, __shfl_xor(mx, 16));
      mx = fmaxf(mx, __shfl_xor(mx, 32));
      float mnew  = fmaxf(m_i[i], mx);
      float alpha = __builtin_amdgcn_exp2f(m_i[i] - mnew);
      m_i[i] = mnew;
      float rs = 0.f;
#pragma unroll
      for (int j = 0; j < 4; j++)
#pragma unroll
        for (int r = 0; r < 4; r++) {
          float pv = __builtin_amdgcn_exp2f(st[j][i][r] - mnew);
          ph[i][j][r] = (_Float16)pv;
          rs += pv;
        }
      l_p[i] = l_p[i] * alpha + rs;
      if (__any(alpha < 1.0f)) {
#pragma unroll
        for (int r = 0; r < 4; r++) {
          float a_r = __shfl(alpha, lq * 4 + r);
#pragma unroll
          for (int jd = 0; jd < 8; jd++) oacc[i][jd][r] *= a_r;
        }
      }
    }

    // ---- O += P V via 16x16x16 (A = ph in-register, B = Vt half4)
#pragma unroll
    for (int j = 0; j < 4; j++) {
#pragma unroll
      for (int jd = 0; jd < 8; jd++) {
        half4 vb = *(const half4*)&Vt[cur][jd * 16 + l15][j * 16 + lq * 4];
#pragma unroll
        for (int i = 0; i < 2; i++)
          oacc[i][jd] = __builtin_amdgcn_mfma_f32_16x16x16f16(ph[i][j], vb, oacc[i][jd], 0, 0, 0);
      }
    }

    if (has_next) {
      const int nxt = 1 - cur;
#pragma unroll
      for (int it = 0; it < 4; it++) {
        *(half8*)&Ks[nxt][krow[it]][kcol[it]] = kreg[it];
        *(half8*)&Vt[nxt][vrow[it]][vcol[it]] = vreg[it];
      }
    }
    __syncthreads();
  }

  // ---- final l reduction + epilogue
#pragma unroll
  for (int i = 0; i < 2; i++) {
    float l = l_p[i];
    l += __shfl_xor(l, 16);
    l += __shfl_xor(l, 32);
    float linv = 1.0f / l;
#pragma unroll
    for (int r = 0; r < 4; r++) {
      float lr = __shfl(linv, lq * 4 + r);
      size_t row = (size_t)(b * S_ + q0 + wave * 32 + i * 16 + lq * 4 + r);
#pragma unroll
      for (int jd = 0; jd < 8; jd++)
        Obuf[row * HID_ + h * HD_ + jd * 16 + l15] = (_Float16)(oacc[i][jd][r] * lr);
    }
  }
}

// ---------------------------------------------------------------------------
extern "C" void kernel_launch(void* const* d_in, const int* in_sizes, int n_in,
                              void* d_out, int out_size, void* d_ws, size_t ws_size,
                              hipStream_t stream) {
  const float* hidden = (const float*)d_in[0];
  const int*   mask   = (const int*)d_in[1];
  const float* Wq = (const float*)d_in[2];
  const float* bq = (const float*)d_in[3];
  const float* Wk = (const float*)d_in[4];
  const float* bk = (const float*)d_in[5];
  const float* Wv = (const float*)d_in[6];
  const float* bv = (const float*)d_in[7];
  const float* Wo = (const float*)d_in[8];
  const float* bo = (const float*)d_in[9];
  float* out = (float*)d_out;

  char* p = (char*)d_ws;
  auto alloc = [&](size_t bytes) {
    char* r = p;
    p += (bytes + 255) & ~(size_t)255;
    return r;
  };
  _Float16* hidh  = (_Float16*)alloc((size_t)M_ * HID_ * 2);
  _Float16* Wqh   = (_Float16*)alloc((size_t)HID_ * HID_ * 2);
  _Float16* Wkh   = (_Float16*)alloc((size_t)HD_ * HID_ * 2);
  _Float16* Wvh   = (_Float16*)alloc((size_t)HD_ * HID_ * 2);
  _Float16* Woh   = (_Float16*)alloc((size_t)HID_ * HID_ * 2);
  _Float16* Qh    = (_Float16*)alloc((size_t)M_ * HID_ * 2);
  _Float16* Kh    = (_Float16*)alloc((size_t)M_ * HD_ * 2);
  _Float16* VhT   = (_Float16*)alloc((size_t)M_ * HD_ * 2);
  _Float16* attnh = (_Float16*)alloc((size_t)M_ * HID_ * 2);

  // one fused fp32 -> fp16 cast (8448 blocks)
  cvt_all<<<8448, 256, 0, stream>>>(hidden, Wq, Wk, Wv, Wo,
                                    hidh, Wqh, Wkh, Wvh, Woh);

  // fused Q/K/V projection (V written transposed): 18 x 32 tiles
  dim3 gqkv(18, M_ / 128);
  gemm_qkv<<<gqkv, 256, 0, stream>>>(hidh, Wqh, bq, Qh, Wkh, bk, Kh, Wvh, bv, VhT);

  // attention (S^T flash, dbuf K/V)
  dim3 ga(S_ / 128, B_ * NH_);  // (16, 32)
  attn_mfma<<<ga, 256, 0, stream>>>(Qh, Kh, VhT, mask, attnh);

  // output projection -> d_out (fp32)
  dim3 go(HID_ / 128, M_ / 128);
  gemm_out<<<go, 256, 0, stream>>>(attnh, Woh, bo, out);
}